// Round 13
// baseline (228.105 us; speedup 1.0000x reference)
//
#include <hip/hip_runtime.h>

typedef unsigned short ush;
typedef unsigned int u32;
typedef __attribute__((ext_vector_type(4))) float f32x4;
typedef __attribute__((ext_vector_type(8))) short short8;
typedef __attribute__((ext_vector_type(8))) ush ushx8;
typedef __attribute__((ext_vector_type(4))) ush ushx4;

#define GAS __attribute__((address_space(1)))
#define LAS __attribute__((address_space(3)))

__device__ __forceinline__ void gl_lds16(const void* g, void* l) {
  __builtin_amdgcn_global_load_lds((const GAS void*)g, (LAS void*)l, 16, 0, 0);
}

// manual RNE f32->bf16 (proven)
__device__ __forceinline__ ush f2bf(float f) {
  union { float f; unsigned int u; } x; x.f = f;
  unsigned int r = x.u + 0x7fffu + ((x.u >> 16) & 1u);
  return (ush)(r >> 16);
}
__device__ __forceinline__ u32 fbits(float f) {
  union { float f; u32 u; } x; x.f = f; return x.u;
}

#define NEG_BIG (-1.0e4f)
// 1/sqrt(64) * log2(e): fold softmax scale into exp2
#define SCL 0.18033688f

// ---- convert x: f32 [8192][1024] -> bf16
__global__ __launch_bounds__(256) void k_convert_x(
    const float* __restrict__ X, ush* __restrict__ Xb) {
  int idx = blockIdx.x * 256 + threadIdx.x;
  int base = idx * 8;
  f32x4 a = *(const f32x4*)(X + base);
  f32x4 b = *(const f32x4*)(X + base + 4);
  ushx8 o;
#pragma unroll
  for (int q = 0; q < 4; ++q) { o[q] = f2bf(a[q]); o[4 + q] = f2bf(b[q]); }
  *(ushx8*)(Xb + base) = o;
}

// ---- transpose+convert weights: Wt[z][n][k] = bf16(W[z][k][n]), W f32 1024x1024
__global__ __launch_bounds__(256) void k_transpose_w(
    const float* __restrict__ W0, const float* __restrict__ W1,
    const float* __restrict__ W2, const float* __restrict__ W3,
    ush* __restrict__ Wt) {
  __shared__ ush Ts[64][72];
  const int z = blockIdx.z;
  const float* W = (z == 0) ? W0 : (z == 1) ? W1 : (z == 2) ? W2 : W3;
  ush* Ot = Wt + (size_t)z * 1048576;
  const int k0 = blockIdx.x * 64, n0 = blockIdx.y * 64;
  const int rr = threadIdx.x >> 4, cc = threadIdx.x & 15;
#pragma unroll
  for (int i = 0; i < 4; ++i) {
    int row = i * 16 + rr;
    f32x4 v = *(const f32x4*)(W + (size_t)(k0 + row) * 1024 + n0 + cc * 4);
#pragma unroll
    for (int q = 0; q < 4; ++q) Ts[row][cc * 4 + q] = f2bf(v[q]);
  }
  __syncthreads();
#pragma unroll
  for (int i = 0; i < 4; ++i) {
    int n = i * 16 + rr;
    ushx4 o;
#pragma unroll
    for (int q = 0; q < 4; ++q) o[q] = Ts[cc * 4 + q][n];
    *(ushx4*)(Ot + (size_t)(n0 + n) * 1024 + k0 + cc * 4) = o;
  }
}

// ---- fused QKV GEMM, 256x128 tile, 8 waves, double-buffered counted-vmcnt
// pipeline, XOR-swizzled LDS (pre-swizzled global source; rule-21 pair).
__global__ __launch_bounds__(512, 2) void k_gemm_qkv(
    const ush* __restrict__ X, const ush* __restrict__ Wt, ush* __restrict__ QKV) {
  __shared__ __align__(16) ush As_[2][16384];   // [buf][256 m][64 k] swz key=row&7
  __shared__ __align__(16) ush Bs_[2][8192];    // [buf][128 n][64 k] swz key=row&7
  const int tid = threadIdx.x;
  const int w = tid >> 6, l = tid & 63, lr = l & 15, lg = l >> 4;
  const int wm = w >> 2, wn = w & 3;
  const int mt = blockIdx.x, nt = blockIdx.y;
  const int which = nt >> 3, n0 = (nt & 7) * 128;
  const ush* Ag = X + (size_t)mt * 256 * 1024;
  const ush* Bg = Wt + (size_t)which * 1048576 + (size_t)n0 * 1024;
  int aoff[4], boff[2];
#pragma unroll
  for (int it = 0; it < 4; ++it) {
    int ch = it * 512 + tid, row = ch >> 3, g = ch & 7;
    aoff[it] = row * 1024 + ((g ^ (row & 7)) << 3);
  }
#pragma unroll
  for (int it = 0; it < 2; ++it) {
    int ch = it * 512 + tid, row = ch >> 3, g = ch & 7;
    boff[it] = row * 1024 + ((g ^ (row & 7)) << 3);
  }
  f32x4 acc[8][2] = {};

  auto issueS = [&](int kt, int buf) {
    const ush* Asrc = Ag + kt * 64;
    const ush* Bsrc = Bg + kt * 64;
#pragma unroll
    for (int it = 0; it < 4; ++it)
      gl_lds16(Asrc + aoff[it], &As_[buf][((size_t)it * 512 + tid) * 8]);
#pragma unroll
    for (int it = 0; it < 2; ++it)
      gl_lds16(Bsrc + boff[it], &Bs_[buf][((size_t)it * 512 + tid) * 8]);
  };

  issueS(0, 0);
  for (int t = 0; t < 16; ++t) {
    if (t < 15) {
      issueS(t + 1, (t + 1) & 1);
      asm volatile("s_waitcnt vmcnt(6)" ::: "memory");
    } else {
      asm volatile("s_waitcnt vmcnt(0)" ::: "memory");
    }
    __syncthreads();
    const ush* Ab = As_[t & 1];
    const ush* Bb = Bs_[t & 1];
    short8 fb[2][2];
#pragma unroll
    for (int ni = 0; ni < 2; ++ni)
#pragma unroll
      for (int kk = 0; kk < 2; ++kk) {
        int row = wn * 32 + ni * 16 + lr;
        fb[ni][kk] = *(const short8*)(Bb + row * 64 + (((kk * 4 + lg) ^ (row & 7)) << 3));
      }
#pragma unroll
    for (int qm = 0; qm < 4; ++qm) {
      short8 fa[2][2];
#pragma unroll
      for (int m2 = 0; m2 < 2; ++m2)
#pragma unroll
        for (int kk = 0; kk < 2; ++kk) {
          int row = wm * 128 + (qm * 2 + m2) * 16 + lr;
          fa[m2][kk] = *(const short8*)(Ab + row * 64 + (((kk * 4 + lg) ^ (row & 7)) << 3));
        }
      __builtin_amdgcn_s_setprio(1);
#pragma unroll
      for (int m2 = 0; m2 < 2; ++m2)
#pragma unroll
        for (int ni = 0; ni < 2; ++ni)
#pragma unroll
          for (int kk = 0; kk < 2; ++kk)
            acc[qm * 2 + m2][ni] = __builtin_amdgcn_mfma_f32_16x16x32_bf16(
                fa[m2][kk], fb[ni][kk], acc[qm * 2 + m2][ni], 0, 0, 0);
      __builtin_amdgcn_s_setprio(0);
    }
    __syncthreads();
  }
  ush* Ct = &As_[0][0];
#pragma unroll
  for (int mi = 0; mi < 8; ++mi)
#pragma unroll
    for (int ni = 0; ni < 2; ++ni)
#pragma unroll
      for (int j = 0; j < 4; ++j)
        Ct[(wm * 128 + mi * 16 + lg * 4 + j) * 128 + wn * 32 + ni * 16 + lr] =
            f2bf(acc[mi][ni][j]);
  __syncthreads();
  ush* Om = QKV + (size_t)which * 8388608;
  const int m0 = mt * 256, b = m0 >> 11, t0 = m0 & 2047, h0 = n0 >> 6;
#pragma unroll
  for (int it = 0; it < 8; ++it) {
    int c = it * 512 + tid;
    int hsel = c >> 11;
    int cc = c & 2047;
    int r = cc >> 3;
    int c8 = (cc & 7) * 8;
    ushx8 v = *(const ushx8*)(Ct + r * 128 + hsel * 64 + c8);
    *(ushx8*)(Om + ((size_t)(b * 16 + h0 + hsel) * 2048 + t0 + r) * 64 + c8) = v;
  }
}

// ---- transpose V per head: V[bh][t][64] -> Vtg[bh][64][2048]
__global__ __launch_bounds__(256) void k_transpose_v(
    const ush* __restrict__ V, ush* __restrict__ Vt) {
  __shared__ ush Ts[64][66];
  const int tt = blockIdx.x, bh = blockIdx.y;
  const ush* Vh = V + (size_t)bh * 131072 + tt * 4096;
  ush* Oh = Vt + (size_t)bh * 131072 + tt * 64;
  const int tid = threadIdx.x;
#pragma unroll
  for (int it = 0; it < 2; ++it) {
    int idx = it * 256 + tid;
    int row = idx >> 3, c8 = (idx & 7) * 8;
    ushx8 v = *(const ushx8*)(Vh + row * 64 + c8);
#pragma unroll
    for (int k2 = 0; k2 < 8; ++k2) Ts[row][c8 + k2] = v[k2];
  }
  __syncthreads();
#pragma unroll
  for (int it = 0; it < 2; ++it) {
    int idx = it * 256 + tid;
    int d = idx >> 3, c8 = (idx & 7) * 8;
    ushx8 o;
#pragma unroll
    for (int k2 = 0; k2 < 8; ++k2) o[k2] = Ts[c8 + k2][d];
    *(ushx8*)(Oh + (size_t)d * 2048 + c8) = o;
  }
}

// ---- causal flash attention: balanced pairing, fixed-base softmax,
// fused A+B QK (kf read once), shared Pl with explicit lgkmcnt(0) WAR fence.
__global__ __launch_bounds__(256) void k_attn(
    const ush* __restrict__ Q, const ush* __restrict__ K,
    const ush* __restrict__ Vg, ush* __restrict__ O) {
  __shared__ __align__(16) ush Ks[2][4096];   // swz [64 kv][64 d], key=kv&7
  __shared__ __align__(16) ush Vs[2][4096];   // swz [64 d][64 kv], key=((d&7)+(d>>3))&7
  __shared__ __align__(16) ush Pl[4][1024];   // per-wave P [16 q][64 kv], key=q&7 (A/B share)
  const int lid = blockIdx.x + 16 * blockIdx.y;
  const int qta = (lid >> 3) & 15;
  const int bh  = ((lid >> 7) << 3) | (lid & 7);
  const int qtb = 31 - qta;
  const size_t hb = (size_t)bh * (2048 * 64);
  const ush* Qh = Q + hb;
  const ush* Kh = K + hb;
  const ush* Vh = Vg + hb;                    // [64 d][2048 t]
  const int tid = threadIdx.x, w = tid >> 6, l = tid & 63, lr = l & 15, lg = l >> 4;
  const int q0a = qta * 64 + w * 16, q0b = qtb * 64 + w * 16;

  short8 qfa[2], qfb[2];
#pragma unroll
  for (int s = 0; s < 2; ++s) {
    qfa[s] = *(const short8*)(Qh + (size_t)(q0a + lr) * 64 + s * 32 + lg * 8);
    qfb[s] = *(const short8*)(Qh + (size_t)(q0b + lr) * 64 + s * 32 + lg * 8);
  }
  f32x4 acca[4] = {}, accb[4] = {};
  float la[4] = {0.f, 0.f, 0.f, 0.f}, lb[4] = {0.f, 0.f, 0.f, 0.f};

  int koff[2], voff[2];
#pragma unroll
  for (int it = 0; it < 2; ++it) {
    int ch = it * 256 + tid;
    int r = ch >> 3, g = ch & 7;
    koff[it] = r * 64 + ((g ^ (r & 7)) << 3);
    int keyv = ((r & 7) + (r >> 3)) & 7;
    voff[it] = r * 2048 + ((g ^ keyv) << 3);
  }
  auto issueStage = [&](int c, int buf) {
#pragma unroll
    for (int it = 0; it < 2; ++it) {
      int ch = it * 256 + tid;
      gl_lds16(Kh + (size_t)c * 4096 + koff[it], &Ks[buf][ch * 8]);
      gl_lds16(Vh + c * 64 + voff[it], &Vs[buf][ch * 8]);
    }
  };

  // softmax + PV for one tile's scores (QK already done)
  auto smpv = [&](f32x4* sf, const ush* Vc, f32x4* acc, float* lrow, bool diag) {
    ush* PlW = Pl[w];
#pragma unroll
    for (int f = 0; f < 4; ++f)
#pragma unroll
      for (int j = 0; j < 4; ++j) {
        float vv = sf[f][j] * SCL;
        if (diag && (f * 16 + lr) > (w * 16 + lg * 4 + j)) vv = NEG_BIG;
        sf[f][j] = __builtin_amdgcn_exp2f(vv);
      }
#pragma unroll
    for (int j = 0; j < 4; ++j)
      lrow[j] += (sf[0][j] + sf[1][j]) + (sf[2][j] + sf[3][j]);
#pragma unroll
    for (int f = 0; f < 4; ++f)
#pragma unroll
      for (int j = 0; j < 4; ++j) {
        int q = lg * 4 + j;
        PlW[q * 64 + ((f * 16 + lr) ^ ((q & 7) << 3))] = (ush)(fbits(sf[f][j]) >> 16);
      }
#pragma unroll
    for (int s = 0; s < 2; ++s) {
      short8 pf = *(const short8*)(PlW + lr * 64 + (((s * 4 + lg) ^ (lr & 7)) << 3));
#pragma unroll
      for (int db = 0; db < 4; ++db) {
        int dv = db * 16 + lr;
        int keyv = ((dv & 7) + (dv >> 3)) & 7;
        short8 vf = *(const short8*)(Vc + dv * 64 + (((s * 4 + lg) ^ keyv) << 3));
        acc[db] = __builtin_amdgcn_mfma_f32_16x16x32_bf16(pf, vf, acc[db], 0, 0, 0);
      }
    }
  };

  // fused step: QK for A (if active) and B sharing kf reads, then softmax+PV
  auto ctile2 = [&](const ush* Kc, const ush* Vc, bool actA, bool diagA, bool diagB) {
    f32x4 sfA[4] = {}, sfB[4] = {};
#pragma unroll
    for (int s = 0; s < 2; ++s)
#pragma unroll
      for (int f = 0; f < 4; ++f) {
        int kv = f * 16 + lr;
        short8 kf = *(const short8*)(Kc + kv * 64 + (((s * 4 + lg) ^ (kv & 7)) << 3));
        if (actA)
          sfA[f] = __builtin_amdgcn_mfma_f32_16x16x32_bf16(qfa[s], kf, sfA[f], 0, 0, 0);
        sfB[f] = __builtin_amdgcn_mfma_f32_16x16x32_bf16(qfb[s], kf, sfB[f], 0, 0, 0);
      }
    if (actA) {
      smpv(sfA, Vc, acca, la, diagA);
      // WAR fence: A's pf reads must have returned before B overwrites Pl[w]
      asm volatile("s_waitcnt lgkmcnt(0)" ::: "memory");
    }
    smpv(sfB, Vc, accb, lb, diagB);
  };

  issueStage(0, 0);
  int cur = 0;
  for (int c = 0; c <= qtb; ++c) {
    asm volatile("s_waitcnt vmcnt(0)" ::: "memory");
    __syncthreads();
    if (c < qtb) issueStage(c + 1, cur ^ 1);
    ctile2(Ks[cur], Vs[cur], c <= qta, c == qta, c == qtb);
    __syncthreads();
    cur ^= 1;
  }

#pragma unroll
  for (int msk = 1; msk <= 8; msk <<= 1)
#pragma unroll
    for (int j = 0; j < 4; ++j) {
      la[j] += __shfl_xor(la[j], msk);
      lb[j] += __shfl_xor(lb[j], msk);
    }
  float ia[4], ib[4];
#pragma unroll
  for (int j = 0; j < 4; ++j) {
    ia[j] = __builtin_amdgcn_rcpf(la[j]);
    ib[j] = __builtin_amdgcn_rcpf(lb[j]);
  }
  ush* Oh = O + hb;
#pragma unroll
  for (int db = 0; db < 4; ++db)
#pragma unroll
    for (int j = 0; j < 4; ++j) {
      Oh[(size_t)(q0a + lg * 4 + j) * 64 + db * 16 + lr] = f2bf(acca[db][j] * ia[j]);
      Oh[(size_t)(q0b + lg * 4 + j) * 64 + db * 16 + lr] = f2bf(accb[db][j] * ib[j]);
    }
}

// ---- permute, LDS-tiled: block (jh,tau,b) -> M[b][128*tau..+128][jh*128..+128]
__global__ __launch_bounds__(256) void k_gather(const ush* __restrict__ Ob, ush* __restrict__ Mb) {
  __shared__ ush Ls[2][128][68];
  const int jh = blockIdx.x, tau = blockIdx.y, b = blockIdx.z;
  const int tid = threadIdx.x;
#pragma unroll
  for (int it = 0; it < 8; ++it) {
    int c = it * 256 + tid;
    int r = c >> 3, d8 = (c & 7) * 8;
    int esel = r >> 7, jlow = r & 127;
    ushx8 v = *(const ushx8*)(Ob +
        ((size_t)(b * 16 + jh + esel * 8) * 2048 + jlow * 16 + tau) * 64 + d8);
    *(ushx8*)(&Ls[esel][jlow][d8]) = v;
  }
  __syncthreads();
  const int wv = tid >> 6, l = tid & 63;
  const int e = wv >> 1, jhalf = wv & 1, d = l;
  ush* Mrow = Mb + (size_t)b * 2097152 +
              (size_t)(128 * tau + 2 * d + e) * 1024 + jh * 128 + jhalf * 64;
#pragma unroll
  for (int ch = 0; ch < 8; ++ch) {
    ushx8 v;
#pragma unroll
    for (int k = 0; k < 8; ++k) v[k] = Ls[e][jhalf * 64 + ch * 8 + k][d];
    *(ushx8*)(Mrow + ch * 8) = v;
  }
}

// ---- output GEMM, same 256x128 8-wave pipeline, direct f32 epilogue
__global__ __launch_bounds__(512, 2) void k_gemm_out(
    const ush* __restrict__ A, const ush* __restrict__ Bt, float* __restrict__ Out) {
  __shared__ __align__(16) ush As_[2][16384];
  __shared__ __align__(16) ush Bs_[2][8192];
  const int tid = threadIdx.x;
  const int w = tid >> 6, l = tid & 63, lr = l & 15, lg = l >> 4;
  const int wm = w >> 2, wn = w & 3;
  const int mt = blockIdx.x, nt = blockIdx.y;
  const int n0 = nt * 128;
  const ush* Ag = A + (size_t)mt * 256 * 1024;
  const ush* Bg = Bt + (size_t)n0 * 1024;
  int aoff[4], boff[2];
#pragma unroll
  for (int it = 0; it < 4; ++it) {
    int ch = it * 512 + tid, row = ch >> 3, g = ch & 7;
    aoff[it] = row * 1024 + ((g ^ (row & 7)) << 3);
  }
#pragma unroll
  for (int it = 0; it < 2; ++it) {
    int ch = it * 512 + tid, row = ch >> 3, g = ch & 7;
    boff[it] = row * 1024 + ((g ^ (row & 7)) << 3);
  }
  f32x4 acc[8][2] = {};

  auto issueS = [&](int kt, int buf) {
    const ush* Asrc = Ag + kt * 64;
    const ush* Bsrc = Bg + kt * 64;
#pragma unroll
    for (int it = 0; it < 4; ++it)
      gl_lds16(Asrc + aoff[it], &As_[buf][((size_t)it * 512 + tid) * 8]);
#pragma unroll
    for (int it = 0; it < 2; ++it)
      gl_lds16(Bsrc + boff[it], &Bs_[buf][((size_t)it * 512 + tid) * 8]);
  };

  issueS(0, 0);
  for (int t = 0; t < 16; ++t) {
    if (t < 15) {
      issueS(t + 1, (t + 1) & 1);
      asm volatile("s_waitcnt vmcnt(6)" ::: "memory");
    } else {
      asm volatile("s_waitcnt vmcnt(0)" ::: "memory");
    }
    __syncthreads();
    const ush* Ab = As_[t & 1];
    const ush* Bb = Bs_[t & 1];
    short8 fb[2][2];
#pragma unroll
    for (int ni = 0; ni < 2; ++ni)
#pragma unroll
      for (int kk = 0; kk < 2; ++kk) {
        int row = wn * 32 + ni * 16 + lr;
        fb[ni][kk] = *(const short8*)(Bb + row * 64 + (((kk * 4 + lg) ^ (row & 7)) << 3));
      }
#pragma unroll
    for (int qm = 0; qm < 4; ++qm) {
      short8 fa[2][2];
#pragma unroll
      for (int m2 = 0; m2 < 2; ++m2)
#pragma unroll
        for (int kk = 0; kk < 2; ++kk) {
          int row = wm * 128 + (qm * 2 + m2) * 16 + lr;
          fa[m2][kk] = *(const short8*)(Ab + row * 64 + (((kk * 4 + lg) ^ (row & 7)) << 3));
        }
      __builtin_amdgcn_s_setprio(1);
#pragma unroll
      for (int m2 = 0; m2 < 2; ++m2)
#pragma unroll
        for (int ni = 0; ni < 2; ++ni)
#pragma unroll
          for (int kk = 0; kk < 2; ++kk)
            acc[qm * 2 + m2][ni] = __builtin_amdgcn_mfma_f32_16x16x32_bf16(
                fa[m2][kk], fb[ni][kk], acc[qm * 2 + m2][ni], 0, 0, 0);
      __builtin_amdgcn_s_setprio(0);
    }
    __syncthreads();
  }
  const int m0 = mt * 256;
#pragma unroll
  for (int mi = 0; mi < 8; ++mi)
#pragma unroll
    for (int ni = 0; ni < 2; ++ni)
#pragma unroll
      for (int j = 0; j < 4; ++j)
        Out[(size_t)(m0 + wm * 128 + mi * 16 + lg * 4 + j) * 1024 +
            n0 + wn * 32 + ni * 16 + lr] = acc[mi][ni][j];
}

extern "C" void kernel_launch(void* const* d_in, const int* in_sizes, int n_in,
                              void* d_out, int out_size, void* d_ws, size_t ws_size,
                              hipStream_t stream) {
  const float* x  = (const float*)d_in[0];
  const float* wq = (const float*)d_in[1];
  const float* wk = (const float*)d_in[2];
  const float* wv = (const float*)d_in[3];
  const float* wp = (const float*)d_in[4];
  float* out = (float*)d_out;   // reference output dtype is float32
  char* ws = (char*)d_ws;
  // 72MB layout:
  ush* xb  = (ush*)ws;                 // [0,16MB): x as bf16; dead after qkv GEMM
  ush* wt  = (ush*)(ws + 16777216);    // [16,24MB): Wq^T,Wk^T,Wv^T,Wp^T bf16
  ush* qkv = (ush*)(ws + 25165824);    // [24,72MB): Q,K,V in [B*H][T][64] bf16
  ush* vtg = xb;                       // V^T per head [bh][64][2048] (xb dead)
  ush* ob  = qkv;                      // attn out aliases Q (own-rows read->write)
  ush* mb  = xb;                       // permuted M reuses xb AFTER attn (vtg dead)

  k_convert_x<<<dim3(4096), 256, 0, stream>>>(x, xb);
  k_transpose_w<<<dim3(16, 16, 4), 256, 0, stream>>>(wq, wk, wv, wp, wt);
  k_gemm_qkv<<<dim3(32, 24), 512, 0, stream>>>(xb, wt, qkv);
  k_transpose_v<<<dim3(32, 64), 256, 0, stream>>>(qkv + 16777216, vtg);
  k_attn<<<dim3(16, 64), 256, 0, stream>>>(qkv, qkv + 8388608, vtg, ob);
  k_gather<<<dim3(8, 16, 4), 256, 0, stream>>>(ob, mb);
  k_gemm_out<<<dim3(32, 8), 512, 0, stream>>>(mb, wt + 3145728, out);
}

// Round 14
// 206.720 us; speedup vs baseline: 1.1034x; 1.1034x over previous
//
#include <hip/hip_runtime.h>

typedef unsigned short ush;
typedef unsigned int u32;
typedef __attribute__((ext_vector_type(4))) float f32x4;
typedef __attribute__((ext_vector_type(8))) short short8;
typedef __attribute__((ext_vector_type(8))) ush ushx8;
typedef __attribute__((ext_vector_type(4))) ush ushx4;

#define GAS __attribute__((address_space(1)))
#define LAS __attribute__((address_space(3)))

__device__ __forceinline__ void gl_lds16(const void* g, void* l) {
  __builtin_amdgcn_global_load_lds((const GAS void*)g, (LAS void*)l, 16, 0, 0);
}

// manual RNE f32->bf16 (proven)
__device__ __forceinline__ ush f2bf(float f) {
  union { float f; unsigned int u; } x; x.f = f;
  unsigned int r = x.u + 0x7fffu + ((x.u >> 16) & 1u);
  return (ush)(r >> 16);
}
__device__ __forceinline__ u32 fbits(float f) {
  union { float f; u32 u; } x; x.f = f; return x.u;
}

#define NEG_BIG (-1.0e4f)
// 1/sqrt(64) * log2(e): fold softmax scale into exp2
#define SCL 0.18033688f

// ---- merged prep: blocks [0,4096) convert x f32->bf16; [4096,5120) transpose W
__global__ __launch_bounds__(256) void k_prep(
    const float* __restrict__ X, const float* __restrict__ W0,
    const float* __restrict__ W1, const float* __restrict__ W2,
    const float* __restrict__ W3, ush* __restrict__ Xb, ush* __restrict__ Wt) {
  __shared__ ush Ts[64][72];
  const int bx = blockIdx.x;
  if (bx < 4096) {
    int idx = bx * 256 + threadIdx.x;
    int base = idx * 8;
    f32x4 a = *(const f32x4*)(X + base);
    f32x4 b = *(const f32x4*)(X + base + 4);
    ushx8 o;
#pragma unroll
    for (int q = 0; q < 4; ++q) { o[q] = f2bf(a[q]); o[4 + q] = f2bf(b[q]); }
    *(ushx8*)(Xb + base) = o;
    return;
  }
  const int bid = bx - 4096;
  const int z = bid >> 8;
  const int k0 = (bid & 15) * 64, n0 = ((bid >> 4) & 15) * 64;
  const float* W = (z == 0) ? W0 : (z == 1) ? W1 : (z == 2) ? W2 : W3;
  ush* Ot = Wt + (size_t)z * 1048576;
  const int rr = threadIdx.x >> 4, cc = threadIdx.x & 15;
#pragma unroll
  for (int i = 0; i < 4; ++i) {
    int row = i * 16 + rr;
    f32x4 v = *(const f32x4*)(W + (size_t)(k0 + row) * 1024 + n0 + cc * 4);
#pragma unroll
    for (int q = 0; q < 4; ++q) Ts[row][cc * 4 + q] = f2bf(v[q]);
  }
  __syncthreads();
#pragma unroll
  for (int i = 0; i < 4; ++i) {
    int n = i * 16 + rr;
    ushx4 o;
#pragma unroll
    for (int q = 0; q < 4; ++q) o[q] = Ts[cc * 4 + q][n];
    *(ushx4*)(Ot + (size_t)(n0 + n) * 1024 + k0 + cc * 4) = o;
  }
}

// ---- fused QKV GEMM, 256x128 tile, 8 waves, double-buffered counted-vmcnt
// pipeline, XOR-swizzled LDS. V blocks (which==2) write V^T [bh][d][t] directly.
__global__ __launch_bounds__(512, 2) void k_gemm_qkv(
    const ush* __restrict__ X, const ush* __restrict__ Wt,
    ush* __restrict__ QKV, ush* __restrict__ Vtg) {
  __shared__ __align__(16) ush As_[2][16384];   // [buf][256 m][64 k] swz key=row&7
  __shared__ __align__(16) ush Bs_[2][8192];    // [buf][128 n][64 k] swz key=row&7
  const int tid = threadIdx.x;
  const int w = tid >> 6, l = tid & 63, lr = l & 15, lg = l >> 4;
  const int wm = w >> 2, wn = w & 3;
  const int mt = blockIdx.x, nt = blockIdx.y;
  const int which = nt >> 3, n0 = (nt & 7) * 128;
  const ush* Ag = X + (size_t)mt * 256 * 1024;
  const ush* Bg = Wt + (size_t)which * 1048576 + (size_t)n0 * 1024;
  int aoff[4], boff[2];
#pragma unroll
  for (int it = 0; it < 4; ++it) {
    int ch = it * 512 + tid, row = ch >> 3, g = ch & 7;
    aoff[it] = row * 1024 + ((g ^ (row & 7)) << 3);
  }
#pragma unroll
  for (int it = 0; it < 2; ++it) {
    int ch = it * 512 + tid, row = ch >> 3, g = ch & 7;
    boff[it] = row * 1024 + ((g ^ (row & 7)) << 3);
  }
  f32x4 acc[8][2] = {};

  auto issueS = [&](int kt, int buf) {
    const ush* Asrc = Ag + kt * 64;
    const ush* Bsrc = Bg + kt * 64;
#pragma unroll
    for (int it = 0; it < 4; ++it)
      gl_lds16(Asrc + aoff[it], &As_[buf][((size_t)it * 512 + tid) * 8]);
#pragma unroll
    for (int it = 0; it < 2; ++it)
      gl_lds16(Bsrc + boff[it], &Bs_[buf][((size_t)it * 512 + tid) * 8]);
  };

  issueS(0, 0);
  for (int t = 0; t < 16; ++t) {
    if (t < 15) {
      issueS(t + 1, (t + 1) & 1);
      asm volatile("s_waitcnt vmcnt(6)" ::: "memory");
    } else {
      asm volatile("s_waitcnt vmcnt(0)" ::: "memory");
    }
    __syncthreads();
    const ush* Ab = As_[t & 1];
    const ush* Bb = Bs_[t & 1];
    short8 fb[2][2];
#pragma unroll
    for (int ni = 0; ni < 2; ++ni)
#pragma unroll
      for (int kk = 0; kk < 2; ++kk) {
        int row = wn * 32 + ni * 16 + lr;
        fb[ni][kk] = *(const short8*)(Bb + row * 64 + (((kk * 4 + lg) ^ (row & 7)) << 3));
      }
#pragma unroll
    for (int qm = 0; qm < 4; ++qm) {
      short8 fa[2][2];
#pragma unroll
      for (int m2 = 0; m2 < 2; ++m2)
#pragma unroll
        for (int kk = 0; kk < 2; ++kk) {
          int row = wm * 128 + (qm * 2 + m2) * 16 + lr;
          fa[m2][kk] = *(const short8*)(Ab + row * 64 + (((kk * 4 + lg) ^ (row & 7)) << 3));
        }
      __builtin_amdgcn_s_setprio(1);
#pragma unroll
      for (int m2 = 0; m2 < 2; ++m2)
#pragma unroll
        for (int ni = 0; ni < 2; ++ni)
#pragma unroll
          for (int kk = 0; kk < 2; ++kk)
            acc[qm * 2 + m2][ni] = __builtin_amdgcn_mfma_f32_16x16x32_bf16(
                fa[m2][kk], fb[ni][kk], acc[qm * 2 + m2][ni], 0, 0, 0);
      __builtin_amdgcn_s_setprio(0);
    }
    __syncthreads();
  }
  ush* Ct = &As_[0][0];
#pragma unroll
  for (int mi = 0; mi < 8; ++mi)
#pragma unroll
    for (int ni = 0; ni < 2; ++ni)
#pragma unroll
      for (int j = 0; j < 4; ++j)
        Ct[(wm * 128 + mi * 16 + lg * 4 + j) * 128 + wn * 32 + ni * 16 + lr] =
            f2bf(acc[mi][ni][j]);
  __syncthreads();
  const int m0 = mt * 256, b = m0 >> 11, t0 = m0 & 2047, h0 = n0 >> 6;
  if (which == 2) {
    // V^T write: vtg[b*16+h0+hsel][d][t0 + r] from Ct columns.
    // Per instruction: row fixed, cc stride 2B -> 2-way bank (free).
    const int cc = tid & 127, rq = tid >> 7;
    const int hsel = cc >> 6, d = cc & 63;
    ush* dst = Vtg + (size_t)(b * 16 + h0 + hsel) * 131072 + (size_t)d * 2048 +
               t0 + rq * 64;
#pragma unroll
    for (int ch = 0; ch < 8; ++ch) {
      ushx8 v;
#pragma unroll
      for (int k = 0; k < 8; ++k) v[k] = Ct[(rq * 64 + ch * 8 + k) * 128 + cc];
      *(ushx8*)(dst + ch * 8) = v;
    }
  } else {
    ush* Om = QKV + (size_t)which * 8388608;
#pragma unroll
    for (int it = 0; it < 8; ++it) {
      int c = it * 512 + tid;
      int hsel = c >> 11;
      int cc = c & 2047;
      int r = cc >> 3;
      int c8 = (cc & 7) * 8;
      ushx8 v = *(const ushx8*)(Ct + r * 128 + hsel * 64 + c8);
      *(ushx8*)(Om + ((size_t)(b * 16 + h0 + hsel) * 2048 + t0 + r) * 64 + c8) = v;
    }
  }
}

// ---- causal flash attention (round-12 structure, single barrier per step).
// Proof of barrier elision: step c+1's leading __syncthreads guarantees all
// waves finished compute(c) (their ds_reads completed -- data feeds MFMAs via
// compiler lgkmcnt waits) before issueStage(c+2) overwrites buf[c&1].
__global__ __launch_bounds__(256) void k_attn(
    const ush* __restrict__ Q, const ush* __restrict__ K,
    const ush* __restrict__ Vg, ush* __restrict__ O) {
  __shared__ __align__(16) ush Ks[2][4096];   // swz [64 kv][64 d], key=kv&7
  __shared__ __align__(16) ush Vs[2][4096];   // swz [64 d][64 kv], key=((d&7)+(d>>3))&7
  __shared__ __align__(16) ush Pl[8][1024];   // per wave x {A,B}: swz [16 q][64 kv], key=q&7
  const int lid = blockIdx.x + 16 * blockIdx.y;
  const int qta = (lid >> 3) & 15;
  const int bh  = ((lid >> 7) << 3) | (lid & 7);
  const int qtb = 31 - qta;
  const size_t hb = (size_t)bh * (2048 * 64);
  const ush* Qh = Q + hb;
  const ush* Kh = K + hb;
  const ush* Vh = Vg + hb;                    // [64 d][2048 t]
  const int tid = threadIdx.x, w = tid >> 6, l = tid & 63, lr = l & 15, lg = l >> 4;
  const int q0a = qta * 64 + w * 16, q0b = qtb * 64 + w * 16;

  short8 qfa[2], qfb[2];
#pragma unroll
  for (int s = 0; s < 2; ++s) {
    qfa[s] = *(const short8*)(Qh + (size_t)(q0a + lr) * 64 + s * 32 + lg * 8);
    qfb[s] = *(const short8*)(Qh + (size_t)(q0b + lr) * 64 + s * 32 + lg * 8);
  }
  f32x4 acca[4] = {}, accb[4] = {};
  float la[4] = {0.f, 0.f, 0.f, 0.f}, lb[4] = {0.f, 0.f, 0.f, 0.f};

  int koff[2], voff[2];
#pragma unroll
  for (int it = 0; it < 2; ++it) {
    int ch = it * 256 + tid;
    int r = ch >> 3, g = ch & 7;
    koff[it] = r * 64 + ((g ^ (r & 7)) << 3);
    int keyv = ((r & 7) + (r >> 3)) & 7;
    voff[it] = r * 2048 + ((g ^ keyv) << 3);
  }
  auto issueStage = [&](int c, int buf) {
#pragma unroll
    for (int it = 0; it < 2; ++it) {
      int ch = it * 256 + tid;
      gl_lds16(Kh + (size_t)c * 4096 + koff[it], &Ks[buf][ch * 8]);
      gl_lds16(Vh + c * 64 + voff[it], &Vs[buf][ch * 8]);
    }
  };

  auto ctile = [&](const ush* Kc, const ush* Vc, const short8* qf,
                   f32x4* acc, float* lrow, bool diag, ush* PlW) {
    f32x4 sf[4] = {};
#pragma unroll
    for (int s = 0; s < 2; ++s)
#pragma unroll
      for (int f = 0; f < 4; ++f) {
        int kv = f * 16 + lr;
        short8 kf = *(const short8*)(Kc + kv * 64 + (((s * 4 + lg) ^ (kv & 7)) << 3));
        sf[f] = __builtin_amdgcn_mfma_f32_16x16x32_bf16(qf[s], kf, sf[f], 0, 0, 0);
      }
#pragma unroll
    for (int f = 0; f < 4; ++f)
#pragma unroll
      for (int j = 0; j < 4; ++j) {
        float vv = sf[f][j] * SCL;
        if (diag && (f * 16 + lr) > (w * 16 + lg * 4 + j)) vv = NEG_BIG;
        sf[f][j] = __builtin_amdgcn_exp2f(vv);
      }
#pragma unroll
    for (int j = 0; j < 4; ++j)
      lrow[j] += (sf[0][j] + sf[1][j]) + (sf[2][j] + sf[3][j]);
#pragma unroll
    for (int f = 0; f < 4; ++f)
#pragma unroll
      for (int j = 0; j < 4; ++j) {
        int q = lg * 4 + j;
        PlW[q * 64 + ((f * 16 + lr) ^ ((q & 7) << 3))] = (ush)(fbits(sf[f][j]) >> 16);
      }
#pragma unroll
    for (int s = 0; s < 2; ++s) {
      short8 pf = *(const short8*)(PlW + lr * 64 + (((s * 4 + lg) ^ (lr & 7)) << 3));
#pragma unroll
      for (int db = 0; db < 4; ++db) {
        int dv = db * 16 + lr;
        int keyv = ((dv & 7) + (dv >> 3)) & 7;
        short8 vf = *(const short8*)(Vc + dv * 64 + (((s * 4 + lg) ^ keyv) << 3));
        acc[db] = __builtin_amdgcn_mfma_f32_16x16x32_bf16(pf, vf, acc[db], 0, 0, 0);
      }
    }
  };

  issueStage(0, 0);
  int cur = 0;
  for (int c = 0; c <= qtb; ++c) {
    asm volatile("s_waitcnt vmcnt(0)" ::: "memory");
    __syncthreads();                  // buf[cur] staged; also fences prev compute
    if (c < qtb) issueStage(c + 1, cur ^ 1);
    const ush* Kc = Ks[cur];
    const ush* Vc = Vs[cur];
    if (c <= qta) ctile(Kc, Vc, qfa, acca, la, c == qta, Pl[w]);
    ctile(Kc, Vc, qfb, accb, lb, c == qtb, Pl[4 + w]);
    cur ^= 1;
  }

#pragma unroll
  for (int msk = 1; msk <= 8; msk <<= 1)
#pragma unroll
    for (int j = 0; j < 4; ++j) {
      la[j] += __shfl_xor(la[j], msk);
      lb[j] += __shfl_xor(lb[j], msk);
    }
  float ia[4], ib[4];
#pragma unroll
  for (int j = 0; j < 4; ++j) {
    ia[j] = __builtin_amdgcn_rcpf(la[j]);
    ib[j] = __builtin_amdgcn_rcpf(lb[j]);
  }
  ush* Oh = O + hb;
#pragma unroll
  for (int db = 0; db < 4; ++db)
#pragma unroll
    for (int j = 0; j < 4; ++j) {
      Oh[(size_t)(q0a + lg * 4 + j) * 64 + db * 16 + lr] = f2bf(acca[db][j] * ia[j]);
      Oh[(size_t)(q0b + lg * 4 + j) * 64 + db * 16 + lr] = f2bf(accb[db][j] * ib[j]);
    }
}

// ---- permute, LDS-tiled: block (jh,tau,b) -> M[b][128*tau..+128][jh*128..+128]
__global__ __launch_bounds__(256) void k_gather(const ush* __restrict__ Ob, ush* __restrict__ Mb) {
  __shared__ ush Ls[2][128][68];
  const int jh = blockIdx.x, tau = blockIdx.y, b = blockIdx.z;
  const int tid = threadIdx.x;
#pragma unroll
  for (int it = 0; it < 8; ++it) {
    int c = it * 256 + tid;
    int r = c >> 3, d8 = (c & 7) * 8;
    int esel = r >> 7, jlow = r & 127;
    ushx8 v = *(const ushx8*)(Ob +
        ((size_t)(b * 16 + jh + esel * 8) * 2048 + jlow * 16 + tau) * 64 + d8);
    *(ushx8*)(&Ls[esel][jlow][d8]) = v;
  }
  __syncthreads();
  const int wv = tid >> 6, l = tid & 63;
  const int e = wv >> 1, jhalf = wv & 1, d = l;
  ush* Mrow = Mb + (size_t)b * 2097152 +
              (size_t)(128 * tau + 2 * d + e) * 1024 + jh * 128 + jhalf * 64;
#pragma unroll
  for (int ch = 0; ch < 8; ++ch) {
    ushx8 v;
#pragma unroll
    for (int k = 0; k < 8; ++k) v[k] = Ls[e][jhalf * 64 + ch * 8 + k][d];
    *(ushx8*)(Mrow + ch * 8) = v;
  }
}

// ---- output GEMM, same 256x128 8-wave pipeline, direct f32 epilogue
__global__ __launch_bounds__(512, 2) void k_gemm_out(
    const ush* __restrict__ A, const ush* __restrict__ Bt, float* __restrict__ Out) {
  __shared__ __align__(16) ush As_[2][16384];
  __shared__ __align__(16) ush Bs_[2][8192];
  const int tid = threadIdx.x;
  const int w = tid >> 6, l = tid & 63, lr = l & 15, lg = l >> 4;
  const int wm = w >> 2, wn = w & 3;
  const int mt = blockIdx.x, nt = blockIdx.y;
  const int n0 = nt * 128;
  const ush* Ag = A + (size_t)mt * 256 * 1024;
  const ush* Bg = Bt + (size_t)n0 * 1024;
  int aoff[4], boff[2];
#pragma unroll
  for (int it = 0; it < 4; ++it) {
    int ch = it * 512 + tid, row = ch >> 3, g = ch & 7;
    aoff[it] = row * 1024 + ((g ^ (row & 7)) << 3);
  }
#pragma unroll
  for (int it = 0; it < 2; ++it) {
    int ch = it * 512 + tid, row = ch >> 3, g = ch & 7;
    boff[it] = row * 1024 + ((g ^ (row & 7)) << 3);
  }
  f32x4 acc[8][2] = {};

  auto issueS = [&](int kt, int buf) {
    const ush* Asrc = Ag + kt * 64;
    const ush* Bsrc = Bg + kt * 64;
#pragma unroll
    for (int it = 0; it < 4; ++it)
      gl_lds16(Asrc + aoff[it], &As_[buf][((size_t)it * 512 + tid) * 8]);
#pragma unroll
    for (int it = 0; it < 2; ++it)
      gl_lds16(Bsrc + boff[it], &Bs_[buf][((size_t)it * 512 + tid) * 8]);
  };

  issueS(0, 0);
  for (int t = 0; t < 16; ++t) {
    if (t < 15) {
      issueS(t + 1, (t + 1) & 1);
      asm volatile("s_waitcnt vmcnt(6)" ::: "memory");
    } else {
      asm volatile("s_waitcnt vmcnt(0)" ::: "memory");
    }
    __syncthreads();
    const ush* Ab = As_[t & 1];
    const ush* Bb = Bs_[t & 1];
    short8 fb[2][2];
#pragma unroll
    for (int ni = 0; ni < 2; ++ni)
#pragma unroll
      for (int kk = 0; kk < 2; ++kk) {
        int row = wn * 32 + ni * 16 + lr;
        fb[ni][kk] = *(const short8*)(Bb + row * 64 + (((kk * 4 + lg) ^ (row & 7)) << 3));
      }
#pragma unroll
    for (int qm = 0; qm < 4; ++qm) {
      short8 fa[2][2];
#pragma unroll
      for (int m2 = 0; m2 < 2; ++m2)
#pragma unroll
        for (int kk = 0; kk < 2; ++kk) {
          int row = wm * 128 + (qm * 2 + m2) * 16 + lr;
          fa[m2][kk] = *(const short8*)(Ab + row * 64 + (((kk * 4 + lg) ^ (row & 7)) << 3));
        }
      __builtin_amdgcn_s_setprio(1);
#pragma unroll
      for (int m2 = 0; m2 < 2; ++m2)
#pragma unroll
        for (int ni = 0; ni < 2; ++ni)
#pragma unroll
          for (int kk = 0; kk < 2; ++kk)
            acc[qm * 2 + m2][ni] = __builtin_amdgcn_mfma_f32_16x16x32_bf16(
                fa[m2][kk], fb[ni][kk], acc[qm * 2 + m2][ni], 0, 0, 0);
      __builtin_amdgcn_s_setprio(0);
    }
    __syncthreads();
  }
  const int m0 = mt * 256;
#pragma unroll
  for (int mi = 0; mi < 8; ++mi)
#pragma unroll
    for (int ni = 0; ni < 2; ++ni)
#pragma unroll
      for (int j = 0; j < 4; ++j)
        Out[(size_t)(m0 + wm * 128 + mi * 16 + lg * 4 + j) * 1024 +
            n0 + wn * 32 + ni * 16 + lr] = acc[mi][ni][j];
}

extern "C" void kernel_launch(void* const* d_in, const int* in_sizes, int n_in,
                              void* d_out, int out_size, void* d_ws, size_t ws_size,
                              hipStream_t stream) {
  const float* x  = (const float*)d_in[0];
  const float* wq = (const float*)d_in[1];
  const float* wk = (const float*)d_in[2];
  const float* wv = (const float*)d_in[3];
  const float* wp = (const float*)d_in[4];
  float* out = (float*)d_out;   // reference output dtype is float32
  char* ws = (char*)d_ws;
  // 88MB layout (r1 ran with 88MB: available):
  ush* xb  = (ush*)ws;                 // [0,16MB): x bf16; dead after qkv GEMM
  ush* wt  = (ush*)(ws + 16777216);    // [16,24MB): Wq^T,Wk^T,Wv^T,Wp^T bf16
  ush* qkv = (ush*)(ws + 25165824);    // [24,72MB): Q,K (V slot unused)
  ush* vtg = (ush*)(ws + 75497472);    // [72,88MB): V^T [bh][64][2048]
  ush* ob  = qkv;                      // attn out aliases Q (own-rows r->w)
  ush* mb  = xb;                       // permuted M reuses xb after attn

  k_prep<<<dim3(5120), 256, 0, stream>>>(x, wq, wk, wv, wp, xb, wt);
  k_gemm_qkv<<<dim3(32, 24), 512, 0, stream>>>(xb, wt, qkv, vtg);
  k_attn<<<dim3(16, 64), 256, 0, stream>>>(qkv, qkv + 8388608, vtg, ob);
  k_gather<<<dim3(8, 16, 4), 256, 0, stream>>>(ob, mb);
  k_gemm_out<<<dim3(32, 8), 512, 0, stream>>>(mb, wt + 3145728, out);
}

// Round 15
// 195.259 us; speedup vs baseline: 1.1682x; 1.0587x over previous
//
#include <hip/hip_runtime.h>

typedef unsigned short ush;
typedef unsigned int u32;
typedef __attribute__((ext_vector_type(4))) float f32x4;
typedef __attribute__((ext_vector_type(8))) short short8;
typedef __attribute__((ext_vector_type(8))) ush ushx8;
typedef __attribute__((ext_vector_type(4))) ush ushx4;

#define GAS __attribute__((address_space(1)))
#define LAS __attribute__((address_space(3)))

__device__ __forceinline__ void gl_lds16(const void* g, void* l) {
  __builtin_amdgcn_global_load_lds((const GAS void*)g, (LAS void*)l, 16, 0, 0);
}

// manual RNE f32->bf16 (proven)
__device__ __forceinline__ ush f2bf(float f) {
  union { float f; unsigned int u; } x; x.f = f;
  unsigned int r = x.u + 0x7fffu + ((x.u >> 16) & 1u);
  return (ush)(r >> 16);
}
__device__ __forceinline__ u32 fbits(float f) {
  union { float f; u32 u; } x; x.f = f; return x.u;
}

#define NEG_BIG (-1.0e4f)
// 1/sqrt(64) * log2(e): fold softmax scale into exp2
#define SCL 0.18033688f

// BK=32 row swizzle: 4 chunks (16B) per row, key spreads 16-lane row-groups
__device__ __forceinline__ int kkey(int row) { return ((row & 3) + (row >> 2)) & 3; }

// ---- merged prep: blocks [0,4096) convert x f32->bf16; [4096,5120) transpose W
__global__ __launch_bounds__(256) void k_prep(
    const float* __restrict__ X, const float* __restrict__ W0,
    const float* __restrict__ W1, const float* __restrict__ W2,
    const float* __restrict__ W3, ush* __restrict__ Xb, ush* __restrict__ Wt) {
  __shared__ ush Ts[64][72];
  const int bx = blockIdx.x;
  if (bx < 4096) {
    int idx = bx * 256 + threadIdx.x;
    int base = idx * 8;
    f32x4 a = *(const f32x4*)(X + base);
    f32x4 b = *(const f32x4*)(X + base + 4);
    ushx8 o;
#pragma unroll
    for (int q = 0; q < 4; ++q) { o[q] = f2bf(a[q]); o[4 + q] = f2bf(b[q]); }
    *(ushx8*)(Xb + base) = o;
    return;
  }
  const int bid = bx - 4096;
  const int z = bid >> 8;
  const int k0 = (bid & 15) * 64, n0 = ((bid >> 4) & 15) * 64;
  const float* W = (z == 0) ? W0 : (z == 1) ? W1 : (z == 2) ? W2 : W3;
  ush* Ot = Wt + (size_t)z * 1048576;
  const int rr = threadIdx.x >> 4, cc = threadIdx.x & 15;
#pragma unroll
  for (int i = 0; i < 4; ++i) {
    int row = i * 16 + rr;
    f32x4 v = *(const f32x4*)(W + (size_t)(k0 + row) * 1024 + n0 + cc * 4);
#pragma unroll
    for (int q = 0; q < 4; ++q) Ts[row][cc * 4 + q] = f2bf(v[q]);
  }
  __syncthreads();
#pragma unroll
  for (int i = 0; i < 4; ++i) {
    int n = i * 16 + rr;
    ushx4 o;
#pragma unroll
    for (int q = 0; q < 4; ++q) o[q] = Ts[cc * 4 + q][n];
    *(ushx4*)(Ot + (size_t)(n0 + n) * 1024 + k0 + cc * 4) = o;
  }
}

// ---- fused QKV GEMM, 256x128 tile, BK=32, 8 waves, TRIPLE-buffered LDS
// (72KB -> 2 blocks/CU), 2-step prefetch distance, counted vmcnt(3),
// single barrier/step. V blocks (which==2) write V^T [bh][d][t] directly.
__global__ __launch_bounds__(512, 2) void k_gemm_qkv(
    const ush* __restrict__ X, const ush* __restrict__ Wt,
    ush* __restrict__ QKV, ush* __restrict__ Vtg) {
  __shared__ __align__(16) ush sm[36864];   // 3 stages x (A 8192 + B 4096) elems
  const int tid = threadIdx.x;
  const int w = tid >> 6, l = tid & 63, lr = l & 15, lg = l >> 4;
  const int wm = w >> 2, wn = w & 3;
  const int mt = blockIdx.x, nt = blockIdx.y;
  const int which = nt >> 3, n0 = (nt & 7) * 128;
  const ush* Ag = X + (size_t)mt * 256 * 1024;
  const ush* Bg = Wt + (size_t)which * 1048576 + (size_t)n0 * 1024;
  // per-thread pre-swizzled global source offsets (involution with read side)
  int aoff[2], boff;
  {
#pragma unroll
    for (int it = 0; it < 2; ++it) {
      int ch = it * 512 + tid, row = ch >> 2, g = ch & 3;
      aoff[it] = row * 1024 + ((g ^ kkey(row)) << 3);
    }
    int row = tid >> 2, g = tid & 3;
    boff = row * 1024 + ((g ^ kkey(row)) << 3);
  }
  f32x4 acc[8][2] = {};

  auto issueS = [&](int kt, int st) {
    const ush* Asrc = Ag + kt * 32;
    const ush* Bsrc = Bg + kt * 32;
    ush* base = sm + st * 12288;
#pragma unroll
    for (int it = 0; it < 2; ++it)
      gl_lds16(Asrc + aoff[it], base + ((size_t)it * 512 + tid) * 8);
    gl_lds16(Bsrc + boff, base + 8192 + (size_t)tid * 8);
  };

  issueS(0, 0);
  issueS(1, 1);
  int st = 0, st2 = 2;
  for (int t = 0; t < 32; ++t) {
    if (t < 31) {
      asm volatile("s_waitcnt vmcnt(3)" ::: "memory");   // stage t landed
    } else {
      asm volatile("s_waitcnt vmcnt(0)" ::: "memory");
    }
    __syncthreads();   // stage t visible to all; all waves done compute(t-1)
    if (t + 2 < 32) issueS(t + 2, st2);  // overwrites buf[(t-1)%3]: safe
    const ush* Ab = sm + st * 12288;
    const ush* Bb = sm + st * 12288 + 8192;
    short8 fb[2];
#pragma unroll
    for (int ni = 0; ni < 2; ++ni) {
      int row = wn * 32 + ni * 16 + lr;
      fb[ni] = *(const short8*)(Bb + row * 32 + ((lg ^ kkey(row)) << 3));
    }
#pragma unroll
    for (int qm = 0; qm < 4; ++qm) {
      short8 fa[2];
#pragma unroll
      for (int m2 = 0; m2 < 2; ++m2) {
        int row = wm * 128 + (qm * 2 + m2) * 16 + lr;
        fa[m2] = *(const short8*)(Ab + row * 32 + ((lg ^ kkey(row)) << 3));
      }
      __builtin_amdgcn_s_setprio(1);
#pragma unroll
      for (int m2 = 0; m2 < 2; ++m2)
#pragma unroll
        for (int ni = 0; ni < 2; ++ni)
          acc[qm * 2 + m2][ni] = __builtin_amdgcn_mfma_f32_16x16x32_bf16(
              fa[m2], fb[ni], acc[qm * 2 + m2][ni], 0, 0, 0);
      __builtin_amdgcn_s_setprio(0);
    }
    st = (st == 2) ? 0 : st + 1;
    st2 = (st2 == 2) ? 0 : st2 + 1;
  }
  __syncthreads();
  // epilogue: bf16 C tile (256x128 = 32768 elems, fits in sm) -> writes
  ush* Ct = sm;
#pragma unroll
  for (int mi = 0; mi < 8; ++mi)
#pragma unroll
    for (int ni = 0; ni < 2; ++ni)
#pragma unroll
      for (int j = 0; j < 4; ++j)
        Ct[(wm * 128 + mi * 16 + lg * 4 + j) * 128 + wn * 32 + ni * 16 + lr] =
            f2bf(acc[mi][ni][j]);
  __syncthreads();
  const int m0 = mt * 256, b = m0 >> 11, t0 = m0 & 2047, h0 = n0 >> 6;
  if (which == 2) {
    // V^T write: vtg[b*16+h0+hsel][d][t0 + r] from Ct columns.
    const int cc = tid & 127, rq = tid >> 7;
    const int hsel = cc >> 6, d = cc & 63;
    ush* dst = Vtg + (size_t)(b * 16 + h0 + hsel) * 131072 + (size_t)d * 2048 +
               t0 + rq * 64;
#pragma unroll
    for (int ch = 0; ch < 8; ++ch) {
      ushx8 v;
#pragma unroll
      for (int k = 0; k < 8; ++k) v[k] = Ct[(rq * 64 + ch * 8 + k) * 128 + cc];
      *(ushx8*)(dst + ch * 8) = v;
    }
  } else {
    ush* Om = QKV + (size_t)which * 8388608;
#pragma unroll
    for (int it = 0; it < 8; ++it) {
      int c = it * 512 + tid;
      int hsel = c >> 11;
      int cc = c & 2047;
      int r = cc >> 3;
      int c8 = (cc & 7) * 8;
      ushx8 v = *(const ushx8*)(Ct + r * 128 + hsel * 64 + c8);
      *(ushx8*)(Om + ((size_t)(b * 16 + h0 + hsel) * 2048 + t0 + r) * 64 + c8) = v;
    }
  }
}

// ---- causal flash attention (round-14 proven structure)
__global__ __launch_bounds__(256) void k_attn(
    const ush* __restrict__ Q, const ush* __restrict__ K,
    const ush* __restrict__ Vg, ush* __restrict__ O) {
  __shared__ __align__(16) ush Ks[2][4096];   // swz [64 kv][64 d], key=kv&7
  __shared__ __align__(16) ush Vs[2][4096];   // swz [64 d][64 kv], key=((d&7)+(d>>3))&7
  __shared__ __align__(16) ush Pl[8][1024];   // per wave x {A,B}: swz [16 q][64 kv], key=q&7
  const int lid = blockIdx.x + 16 * blockIdx.y;
  const int qta = (lid >> 3) & 15;
  const int bh  = ((lid >> 7) << 3) | (lid & 7);
  const int qtb = 31 - qta;
  const size_t hb = (size_t)bh * (2048 * 64);
  const ush* Qh = Q + hb;
  const ush* Kh = K + hb;
  const ush* Vh = Vg + hb;                    // [64 d][2048 t]
  const int tid = threadIdx.x, w = tid >> 6, l = tid & 63, lr = l & 15, lg = l >> 4;
  const int q0a = qta * 64 + w * 16, q0b = qtb * 64 + w * 16;

  short8 qfa[2], qfb[2];
#pragma unroll
  for (int s = 0; s < 2; ++s) {
    qfa[s] = *(const short8*)(Qh + (size_t)(q0a + lr) * 64 + s * 32 + lg * 8);
    qfb[s] = *(const short8*)(Qh + (size_t)(q0b + lr) * 64 + s * 32 + lg * 8);
  }
  f32x4 acca[4] = {}, accb[4] = {};
  float la[4] = {0.f, 0.f, 0.f, 0.f}, lb[4] = {0.f, 0.f, 0.f, 0.f};

  int koff[2], voff[2];
#pragma unroll
  for (int it = 0; it < 2; ++it) {
    int ch = it * 256 + tid;
    int r = ch >> 3, g = ch & 7;
    koff[it] = r * 64 + ((g ^ (r & 7)) << 3);
    int keyv = ((r & 7) + (r >> 3)) & 7;
    voff[it] = r * 2048 + ((g ^ keyv) << 3);
  }
  auto issueStage = [&](int c, int buf) {
#pragma unroll
    for (int it = 0; it < 2; ++it) {
      int ch = it * 256 + tid;
      gl_lds16(Kh + (size_t)c * 4096 + koff[it], &Ks[buf][ch * 8]);
      gl_lds16(Vh + c * 64 + voff[it], &Vs[buf][ch * 8]);
    }
  };

  auto ctile = [&](const ush* Kc, const ush* Vc, const short8* qf,
                   f32x4* acc, float* lrow, bool diag, ush* PlW) {
    f32x4 sf[4] = {};
#pragma unroll
    for (int s = 0; s < 2; ++s)
#pragma unroll
      for (int f = 0; f < 4; ++f) {
        int kv = f * 16 + lr;
        short8 kf = *(const short8*)(Kc + kv * 64 + (((s * 4 + lg) ^ (kv & 7)) << 3));
        sf[f] = __builtin_amdgcn_mfma_f32_16x16x32_bf16(qf[s], kf, sf[f], 0, 0, 0);
      }
#pragma unroll
    for (int f = 0; f < 4; ++f)
#pragma unroll
      for (int j = 0; j < 4; ++j) {
        float vv = sf[f][j] * SCL;
        if (diag && (f * 16 + lr) > (w * 16 + lg * 4 + j)) vv = NEG_BIG;
        sf[f][j] = __builtin_amdgcn_exp2f(vv);
      }
#pragma unroll
    for (int j = 0; j < 4; ++j)
      lrow[j] += (sf[0][j] + sf[1][j]) + (sf[2][j] + sf[3][j]);
#pragma unroll
    for (int f = 0; f < 4; ++f)
#pragma unroll
      for (int j = 0; j < 4; ++j) {
        int q = lg * 4 + j;
        PlW[q * 64 + ((f * 16 + lr) ^ ((q & 7) << 3))] = (ush)(fbits(sf[f][j]) >> 16);
      }
#pragma unroll
    for (int s = 0; s < 2; ++s) {
      short8 pf = *(const short8*)(PlW + lr * 64 + (((s * 4 + lg) ^ (lr & 7)) << 3));
#pragma unroll
      for (int db = 0; db < 4; ++db) {
        int dv = db * 16 + lr;
        int keyv = ((dv & 7) + (dv >> 3)) & 7;
        short8 vf = *(const short8*)(Vc + dv * 64 + (((s * 4 + lg) ^ keyv) << 3));
        acc[db] = __builtin_amdgcn_mfma_f32_16x16x32_bf16(pf, vf, acc[db], 0, 0, 0);
      }
    }
  };

  issueStage(0, 0);
  int cur = 0;
  for (int c = 0; c <= qtb; ++c) {
    asm volatile("s_waitcnt vmcnt(0)" ::: "memory");
    __syncthreads();                  // buf[cur] staged; also fences prev compute
    if (c < qtb) issueStage(c + 1, cur ^ 1);
    const ush* Kc = Ks[cur];
    const ush* Vc = Vs[cur];
    if (c <= qta) ctile(Kc, Vc, qfa, acca, la, c == qta, Pl[w]);
    ctile(Kc, Vc, qfb, accb, lb, c == qtb, Pl[4 + w]);
    cur ^= 1;
  }

#pragma unroll
  for (int msk = 1; msk <= 8; msk <<= 1)
#pragma unroll
    for (int j = 0; j < 4; ++j) {
      la[j] += __shfl_xor(la[j], msk);
      lb[j] += __shfl_xor(lb[j], msk);
    }
  float ia[4], ib[4];
#pragma unroll
  for (int j = 0; j < 4; ++j) {
    ia[j] = __builtin_amdgcn_rcpf(la[j]);
    ib[j] = __builtin_amdgcn_rcpf(lb[j]);
  }
  ush* Oh = O + hb;
#pragma unroll
  for (int db = 0; db < 4; ++db)
#pragma unroll
    for (int j = 0; j < 4; ++j) {
      Oh[(size_t)(q0a + lg * 4 + j) * 64 + db * 16 + lr] = f2bf(acca[db][j] * ia[j]);
      Oh[(size_t)(q0b + lg * 4 + j) * 64 + db * 16 + lr] = f2bf(accb[db][j] * ib[j]);
    }
}

// ---- permute, LDS-tiled: block (jh,tau,b) -> M[b][128*tau..+128][jh*128..+128]
__global__ __launch_bounds__(256) void k_gather(const ush* __restrict__ Ob, ush* __restrict__ Mb) {
  __shared__ ush Ls[2][128][68];
  const int jh = blockIdx.x, tau = blockIdx.y, b = blockIdx.z;
  const int tid = threadIdx.x;
#pragma unroll
  for (int it = 0; it < 8; ++it) {
    int c = it * 256 + tid;
    int r = c >> 3, d8 = (c & 7) * 8;
    int esel = r >> 7, jlow = r & 127;
    ushx8 v = *(const ushx8*)(Ob +
        ((size_t)(b * 16 + jh + esel * 8) * 2048 + jlow * 16 + tau) * 64 + d8);
    *(ushx8*)(&Ls[esel][jlow][d8]) = v;
  }
  __syncthreads();
  const int wv = tid >> 6, l = tid & 63;
  const int e = wv >> 1, jhalf = wv & 1, d = l;
  ush* Mrow = Mb + (size_t)b * 2097152 +
              (size_t)(128 * tau + 2 * d + e) * 1024 + jh * 128 + jhalf * 64;
#pragma unroll
  for (int ch = 0; ch < 8; ++ch) {
    ushx8 v;
#pragma unroll
    for (int k = 0; k < 8; ++k) v[k] = Ls[e][jhalf * 64 + ch * 8 + k][d];
    *(ushx8*)(Mrow + ch * 8) = v;
  }
}

// ---- output GEMM, same 256x128 BK=32 triple-buffer pipeline, f32 epilogue
__global__ __launch_bounds__(512, 2) void k_gemm_out(
    const ush* __restrict__ A, const ush* __restrict__ Bt, float* __restrict__ Out) {
  __shared__ __align__(16) ush sm[36864];
  const int tid = threadIdx.x;
  const int w = tid >> 6, l = tid & 63, lr = l & 15, lg = l >> 4;
  const int wm = w >> 2, wn = w & 3;
  const int mt = blockIdx.x, nt = blockIdx.y;
  const int n0 = nt * 128;
  const ush* Ag = A + (size_t)mt * 256 * 1024;
  const ush* Bg = Bt + (size_t)n0 * 1024;
  int aoff[2], boff;
  {
#pragma unroll
    for (int it = 0; it < 2; ++it) {
      int ch = it * 512 + tid, row = ch >> 2, g = ch & 3;
      aoff[it] = row * 1024 + ((g ^ kkey(row)) << 3);
    }
    int row = tid >> 2, g = tid & 3;
    boff = row * 1024 + ((g ^ kkey(row)) << 3);
  }
  f32x4 acc[8][2] = {};

  auto issueS = [&](int kt, int st) {
    const ush* Asrc = Ag + kt * 32;
    const ush* Bsrc = Bg + kt * 32;
    ush* base = sm + st * 12288;
#pragma unroll
    for (int it = 0; it < 2; ++it)
      gl_lds16(Asrc + aoff[it], base + ((size_t)it * 512 + tid) * 8);
    gl_lds16(Bsrc + boff, base + 8192 + (size_t)tid * 8);
  };

  issueS(0, 0);
  issueS(1, 1);
  int st = 0, st2 = 2;
  for (int t = 0; t < 32; ++t) {
    if (t < 31) {
      asm volatile("s_waitcnt vmcnt(3)" ::: "memory");
    } else {
      asm volatile("s_waitcnt vmcnt(0)" ::: "memory");
    }
    __syncthreads();
    if (t + 2 < 32) issueS(t + 2, st2);
    const ush* Ab = sm + st * 12288;
    const ush* Bb = sm + st * 12288 + 8192;
    short8 fb[2];
#pragma unroll
    for (int ni = 0; ni < 2; ++ni) {
      int row = wn * 32 + ni * 16 + lr;
      fb[ni] = *(const short8*)(Bb + row * 32 + ((lg ^ kkey(row)) << 3));
    }
#pragma unroll
    for (int qm = 0; qm < 4; ++qm) {
      short8 fa[2];
#pragma unroll
      for (int m2 = 0; m2 < 2; ++m2) {
        int row = wm * 128 + (qm * 2 + m2) * 16 + lr;
        fa[m2] = *(const short8*)(Ab + row * 32 + ((lg ^ kkey(row)) << 3));
      }
      __builtin_amdgcn_s_setprio(1);
#pragma unroll
      for (int m2 = 0; m2 < 2; ++m2)
#pragma unroll
        for (int ni = 0; ni < 2; ++ni)
          acc[qm * 2 + m2][ni] = __builtin_amdgcn_mfma_f32_16x16x32_bf16(
              fa[m2], fb[ni], acc[qm * 2 + m2][ni], 0, 0, 0);
      __builtin_amdgcn_s_setprio(0);
    }
    st = (st == 2) ? 0 : st + 1;
    st2 = (st2 == 2) ? 0 : st2 + 1;
  }
  const int m0 = mt * 256;
#pragma unroll
  for (int mi = 0; mi < 8; ++mi)
#pragma unroll
    for (int ni = 0; ni < 2; ++ni)
#pragma unroll
      for (int j = 0; j < 4; ++j)
        Out[(size_t)(m0 + wm * 128 + mi * 16 + lg * 4 + j) * 1024 +
            n0 + wn * 32 + ni * 16 + lr] = acc[mi][ni][j];
}

extern "C" void kernel_launch(void* const* d_in, const int* in_sizes, int n_in,
                              void* d_out, int out_size, void* d_ws, size_t ws_size,
                              hipStream_t stream) {
  const float* x  = (const float*)d_in[0];
  const float* wq = (const float*)d_in[1];
  const float* wk = (const float*)d_in[2];
  const float* wv = (const float*)d_in[3];
  const float* wp = (const float*)d_in[4];
  float* out = (float*)d_out;   // reference output dtype is float32
  char* ws = (char*)d_ws;
  // 88MB layout (r1 ran with 88MB: available):
  ush* xb  = (ush*)ws;                 // [0,16MB): x bf16; dead after qkv GEMM
  ush* wt  = (ush*)(ws + 16777216);    // [16,24MB): Wq^T,Wk^T,Wv^T,Wp^T bf16
  ush* qkv = (ush*)(ws + 25165824);    // [24,72MB): Q,K (V slot unused)
  ush* vtg = (ush*)(ws + 75497472);    // [72,88MB): V^T [bh][64][2048]
  ush* ob  = qkv;                      // attn out aliases Q (own-rows r->w)
  ush* mb  = xb;                       // permuted M reuses xb after attn

  k_prep<<<dim3(5120), 256, 0, stream>>>(x, wq, wk, wv, wp, xb, wt);
  k_gemm_qkv<<<dim3(32, 24), 512, 0, stream>>>(xb, wt, qkv, vtg);
  k_attn<<<dim3(16, 64), 256, 0, stream>>>(qkv, qkv + 8388608, vtg, ob);
  k_gather<<<dim3(8, 16, 4), 256, 0, stream>>>(ob, mb);
  k_gemm_out<<<dim3(32, 8), 512, 0, stream>>>(mb, wt + 3145728, out);
}